// Round 1
// baseline (519.590 us; speedup 1.0000x reference)
//
#include <hip/hip_runtime.h>

// out[token, e] = W[e, idx[token]] + b[e]
// Pass 1: transpose W[128,V] -> Wt[V,128] with bias fused: Wt[v][e] = W[e][v] + b[e]
//         (IEEE-identical to gather-then-add: same single fp32 add of same operands)
// Pass 2: persistent, barrier-free gather: 64-token tiles, grid-stride, 8 independent
//         float4 gathers/thread, nontemporal streaming stores (keep Wt hot in L3).

#define EMB 128

typedef float fx4 __attribute__((ext_vector_type(4)));

// ---- Kernel 1: tiled transpose + bias  W[128,V] -> Wt[V,128] --------------
__global__ void transpose_bias_kernel(const float* __restrict__ W,
                                      const float* __restrict__ bias,
                                      float* __restrict__ Wt, int V) {
    __shared__ float lds[64 * 129];
    const int v0 = blockIdx.x * 64;
    const int t  = threadIdx.x;

    #pragma unroll 8
    for (int j = t; j < 128 * 64; j += 256) {
        const int e    = j >> 6;
        const int vloc = j & 63;
        const int v    = v0 + vloc;
        float val = 0.0f;
        if (v < V) val = W[(size_t)e * V + v];
        lds[vloc * 129 + e] = val;
    }
    __syncthreads();

    #pragma unroll 8
    for (int j = t; j < 64 * 128; j += 256) {
        const int vloc = j >> 7;
        const int e    = j & 127;
        const int v    = v0 + vloc;
        if (v < V) Wt[(size_t)v * EMB + e] = lds[vloc * 129 + e] + bias[e];
    }
}

// ---- Kernel 2: persistent barrier-free gather -----------------------------
// 256 threads/block. Thread t: q = t&31 (float4 slot), g = t>>5 (token subgroup).
// Per 64-token tile: 8 idx loads (32-lane broadcast, L1-hot: tile idx spans 256 B),
// then 8 independent 16-B gathers, then 8 NT stores. No __syncthreads anywhere ->
// loads of the next tile overlap stores of the current one.
__global__ void gather_rows_kernel(const int* __restrict__ idx,
                                   const float* __restrict__ Wt,
                                   float* __restrict__ out, int ntok) {
    const int t = threadIdx.x;
    const int q = t & 31;
    const int g = t >> 5;
    const int ntiles = (ntok + 63) >> 6;

    for (int tile = blockIdx.x; tile < ntiles; tile += gridDim.x) {
        const int tok0 = tile << 6;
        if (tok0 + 64 <= ntok) {
            int rows[8];
            #pragma unroll
            for (int p = 0; p < 8; ++p)
                rows[p] = idx[tok0 + g + (p << 3)];

            fx4 v[8];
            #pragma unroll
            for (int p = 0; p < 8; ++p)
                v[p] = ((const fx4*)(Wt + ((size_t)rows[p] << 7)))[q];

            #pragma unroll
            for (int p = 0; p < 8; ++p)
                __builtin_nontemporal_store(
                    v[p], (fx4*)(out + ((size_t)(tok0 + g + (p << 3)) << 7)) + q);
        } else {
            // guarded tail tile
            #pragma unroll
            for (int p = 0; p < 8; ++p) {
                const int tok = tok0 + g + (p << 3);
                if (tok < ntok) {
                    const int row = idx[tok];
                    fx4 v = ((const fx4*)(Wt + ((size_t)row << 7)))[q];
                    __builtin_nontemporal_store(
                        v, (fx4*)(out + ((size_t)tok << 7)) + q);
                }
            }
        }
    }
}

// ---- Fallback: direct gather if ws too small ------------------------------
__global__ void gather_direct_kernel(const int* __restrict__ idx,
                                     const float* __restrict__ W,
                                     const float* __restrict__ bias,
                                     float* __restrict__ out, int ntok, int V) {
    const long long total  = (long long)ntok * EMB;
    const long long stride = (long long)gridDim.x * blockDim.x;
    for (long long i = (long long)blockIdx.x * blockDim.x + threadIdx.x;
         i < total; i += stride) {
        const int token = (int)(i >> 7);
        const int e     = (int)(i & (EMB - 1));
        out[i] = W[(size_t)e * V + idx[token]] + bias[e];
    }
}

extern "C" void kernel_launch(void* const* d_in, const int* in_sizes, int n_in,
                              void* d_out, int out_size, void* d_ws, size_t ws_size,
                              hipStream_t stream) {
    const int*   x = (const int*)d_in[0];
    const float* W = (const float*)d_in[1];
    const float* b = (const float*)d_in[2];
    float* out = (float*)d_out;

    const int ntok = in_sizes[0];           // 819200
    const int V    = in_sizes[1] / EMB;     // 100000

    const size_t need = (size_t)V * EMB * sizeof(float);  // 51.2 MB
    if (ws_size >= need) {
        float* Wt = (float*)d_ws;
        const int tblocks = (V + 63) / 64;
        transpose_bias_kernel<<<tblocks, 256, 0, stream>>>(W, b, Wt, V);
        // 2560 persistent blocks: 12800 tiles -> exactly 5 tiles/block, barrier-free
        gather_rows_kernel<<<2560, 256, 0, stream>>>(x, Wt, out, ntok);
    } else {
        gather_direct_kernel<<<2048, 256, 0, stream>>>(x, W, b, out, ntok, V);
    }
}

// Round 3
// 518.067 us; speedup vs baseline: 1.0029x; 1.0029x over previous
//
#include <hip/hip_runtime.h>

// out[token, e] = W[e, idx[token]] + b[e]
// Pass 1: transpose W[128,V] -> Wt[V,128], bias fused: Wt[v][e] = W[e][v] + b[e]
//         (IEEE-identical to gather-then-add). W read nontemporally (dead after
//         this pass; keep L3 for Wt).
// Pass 2: deep-ILP persistent gather: 128 tokens per block-iteration,
//         16 independent float4 gathers/thread in flight, next iteration's
//         indices prefetched before current stores (breaks the idx->gather
//         dependency chain across iterations). NT streaming stores.

#define EMB 128

typedef float fx4 __attribute__((ext_vector_type(4)));

// ---- Kernel 1: tiled transpose + bias  W[128,V] -> Wt[V,128] --------------
__global__ void transpose_bias_kernel(const float* __restrict__ W,
                                      const float* __restrict__ bias,
                                      float* __restrict__ Wt, int V) {
    __shared__ float lds[64 * 129];
    const int v0 = blockIdx.x * 64;
    const int t  = threadIdx.x;

    #pragma unroll 8
    for (int j = t; j < 128 * 64; j += 256) {
        const int e    = j >> 6;
        const int vloc = j & 63;
        const int v    = v0 + vloc;
        float val = 0.0f;
        if (v < V) val = __builtin_nontemporal_load(&W[(size_t)e * V + v]);
        lds[vloc * 129 + e] = val;
    }
    __syncthreads();

    #pragma unroll 8
    for (int j = t; j < 64 * 128; j += 256) {
        const int vloc = j >> 7;
        const int e    = j & 127;
        const int v    = v0 + vloc;
        if (v < V) Wt[(size_t)v * EMB + e] = lds[vloc * 129 + e] + bias[e];
    }
}

// ---- Kernel 2: deep-ILP persistent gather ---------------------------------
// 256 threads/block. Thread t: q = t&31 (float4 slot), g = t>>5 (token subgroup).
// Iteration = 128 tokens. Thread handles tokens tok0 + g + p*8, p = 0..15.
// 16 gathers in flight per thread; indices for iteration i+1 issued before
// iteration i's stores.
__global__ __launch_bounds__(256) void gather_rows_deep(
        const int* __restrict__ idx, const float* __restrict__ Wt,
        float* __restrict__ out, int ntok) {
    const int t = threadIdx.x;
    const int q = t & 31;
    const int g = t >> 5;                    // 0..7
    const int niter  = (ntok + 127) >> 7;    // 128-token iterations
    const int stride = gridDim.x;

    int it = blockIdx.x;
    if (it >= niter) return;

    int rows[16];
    {
        const int tok0 = it << 7;
        #pragma unroll
        for (int p = 0; p < 16; ++p) {
            const int tok = tok0 + g + (p << 3);
            rows[p] = (tok < ntok) ? idx[tok] : 0;
        }
    }

    while (it < niter) {
        const int it_n = it + stride;

        // --- prefetch next iteration's indices (issues before gathers/stores)
        int rows_n[16];
        if (it_n < niter) {
            const int tok0n = it_n << 7;
            #pragma unroll
            for (int p = 0; p < 16; ++p) {
                const int tok = tok0n + g + (p << 3);
                rows_n[p] = (tok < ntok) ? idx[tok] : 0;
            }
        } else {
            #pragma unroll
            for (int p = 0; p < 16; ++p) rows_n[p] = 0;
        }

        // --- 16 independent gathers
        fx4 v[16];
        #pragma unroll
        for (int p = 0; p < 16; ++p)
            v[p] = ((const fx4*)(Wt + ((size_t)rows[p] << 7)))[q];

        // --- 16 NT streaming stores (contiguous 512 B per half-wave)
        const int tok0 = it << 7;
        #pragma unroll
        for (int p = 0; p < 16; ++p) {
            const int tok = tok0 + g + (p << 3);
            if (tok < ntok)
                __builtin_nontemporal_store(
                    v[p], (fx4*)(out + ((size_t)tok << 7)) + q);
        }

        #pragma unroll
        for (int p = 0; p < 16; ++p) rows[p] = rows_n[p];
        it = it_n;
    }
}

// ---- Fallback: direct gather if ws too small ------------------------------
__global__ void gather_direct_kernel(const int* __restrict__ idx,
                                     const float* __restrict__ W,
                                     const float* __restrict__ bias,
                                     float* __restrict__ out, int ntok, int V) {
    const long long total  = (long long)ntok * EMB;
    const long long stride = (long long)gridDim.x * blockDim.x;
    for (long long i = (long long)blockIdx.x * blockDim.x + threadIdx.x;
         i < total; i += stride) {
        const int token = (int)(i >> 7);
        const int e     = (int)(i & (EMB - 1));
        out[i] = W[(size_t)e * V + idx[token]] + bias[e];
    }
}

extern "C" void kernel_launch(void* const* d_in, const int* in_sizes, int n_in,
                              void* d_out, int out_size, void* d_ws, size_t ws_size,
                              hipStream_t stream) {
    const int*   x = (const int*)d_in[0];
    const float* W = (const float*)d_in[1];
    const float* b = (const float*)d_in[2];
    float* out = (float*)d_out;

    const int ntok = in_sizes[0];           // 819200
    const int V    = in_sizes[1] / EMB;     // 100000

    const size_t need = (size_t)V * EMB * sizeof(float);  // 51.2 MB
    if (ws_size >= need) {
        float* Wt = (float*)d_ws;
        const int tblocks = (V + 63) / 64;
        transpose_bias_kernel<<<tblocks, 256, 0, stream>>>(W, b, Wt, V);
        // 6400 iterations of 128 tokens; 1280 blocks -> exactly 5 iterations each
        gather_rows_deep<<<1280, 256, 0, stream>>>(x, Wt, out, ntok);
    } else {
        gather_direct_kernel<<<2048, 256, 0, stream>>>(x, W, b, out, ntok, V);
    }
}